// Round 15
// baseline (154.915 us; speedup 1.0000x reference)
//
#include <hip/hip_runtime.h>

#define C 128
#define H 128
#define W 128
#define HW (H*W)

// K1: one (output row, tap-row, ch-half) per small block -> max occupancy.
// grid = 5120 = (b, r, ti 0..4, half); 128 thr = 2 waves x (2x16 ch subgroups).
// lane: s = lane>>5 -> 16-ch subgroup, pg = lane&31 -> 4 px (float4).
__global__ __launch_bounds__(128, 8) void corr_kernel(
    const float* __restrict__ feat, const float* __restrict__ wc,
    float* __restrict__ corrG, float* __restrict__ gG)
{
    __shared__ float corr_s[5][W];   // [j][col] partial for this (ti, half)
    __shared__ float g_s[W];

    const int blk0 = blockIdx.x;
    const int blk  = (blk0 & 7) * 640 + (blk0 >> 3);  // XCD swizzle (5120 = 8*640)
    const int half = blk & 1;
    const int ti   = (blk >> 1) % 5;
    const int rr   = blk / 10;           // b*H + r
    const int b    = rr >> 7;
    const int r    = rr & 127;

    const int tid  = threadIdx.x;
    const int wv   = tid >> 6;           // 0..1
    const int lane = tid & 63;
    const int s    = lane >> 5;          // 16-ch subgroup
    const int pg   = lane & 31;
    const int w0   = pg * 4;             // lane owns cols w0..w0+3

    for (int i = tid; i < 5 * W; i += 128) (&corr_s[0][0])[i] = 0.f;
    if (tid < W) g_s[tid] = 0.f;
    __syncthreads();

    const int  rt    = r - 4 + 2 * ti;   // this block's tap row
    const bool rok   = (unsigned)rt < (unsigned)H;
    const bool isCtr = (ti == 2);

    float acc[5][4];
    float ga[4] = {0.f, 0.f, 0.f, 0.f};
#pragma unroll
    for (int j = 0; j < 5; ++j)
#pragma unroll
        for (int p = 0; p < 4; ++p) acc[j][p] = 0.f;

    if (rok) {
        // window slots: floats [w0-4, w0+8) as 3 aligned float4; a clamped slot
        // is provably fully-OOB for this lane -> its taps are masked below.
        int sb[3];
#pragma unroll
        for (int u = 0; u < 3; ++u) {
            const int cs = w0 - 4 + 4 * u;
            sb[u] = cs < 0 ? 0 : (cs > W - 4 ? W - 4 : cs);
        }
        const int cbase = half * 64 + wv * 32 + s * 16;
        const float* tp = feat + ((size_t)(b * C + cbase) * H + rt) * W;
        const float* cp = feat + ((size_t)(b * C + cbase) * H + r ) * W + w0;
#pragma unroll 2
        for (int c = 0; c < 16; ++c) {
            const float4 A  = *(const float4*)(tp + sb[0]);
            const float4 Bv = *(const float4*)(tp + sb[1]);
            const float4 Cv = *(const float4*)(tp + sb[2]);
            float4 D;
            if (isCtr) D = Bv;           // tap row == center row, sb[1]==w0
            else       D = *(const float4*)cp;
            const float wcv = wc[cbase + c];
            const float win[12] = {A.x, A.y, A.z, A.w,
                                   Bv.x, Bv.y, Bv.z, Bv.w,
                                   Cv.x, Cv.y, Cv.z, Cv.w};
            const float ctr[4] = {D.x, D.y, D.z, D.w};
            if (isCtr) {
#pragma unroll
                for (int p = 0; p < 4; ++p)
                    ga[p] = fmaf(wcv, win[4 + p], ga[p]);
            }
#pragma unroll
            for (int j = 0; j < 5; ++j)
#pragma unroll
                for (int p = 0; p < 4; ++p)
                    acc[j][p] = fmaf(ctr[p], win[p + 2 * j], acc[j][p]);
            tp += HW; cp += HW;
        }
    }

    // combine the two 16-ch subgroups within each wave
#pragma unroll
    for (int j = 0; j < 5; ++j)
#pragma unroll
        for (int p = 0; p < 4; ++p)
            acc[j][p] += __shfl_xor(acc[j][p], 32);
    if (isCtr) {
#pragma unroll
        for (int p = 0; p < 4; ++p) ga[p] += __shfl_xor(ga[p], 32);
    }

    // reduce the 2 waves via LDS atomics (s==0 lanes cover all 128 cols)
    if (s == 0) {
#pragma unroll
        for (int j = 0; j < 5; ++j)
#pragma unroll
            for (int p = 0; p < 4; ++p) {
                const int  col = w0 + p - 4 + 2 * j;
                const bool ok  = rok && ((unsigned)col < (unsigned)W);
                if (ok) atomicAdd(&corr_s[j][w0 + p], acc[j][p]);
            }
        if (isCtr) {
#pragma unroll
            for (int p = 0; p < 4; ++p) atomicAdd(&g_s[w0 + p], ga[p]);
        }
    }
    __syncthreads();

    // store partials (coalesced). corrG layout: [rr][ti][half][5][W]
    float* cg = corrG + (size_t)((rr * 5 + ti) * 2 + half) * (5 * W);
    for (int i = tid; i < 5 * W; i += 128) cg[i] = (&corr_s[0][0])[i];
    if (isCtr && tid < W)
        gG[(size_t)(rr * 2 + half) * W + tid] = g_s[tid];
}

// K2: relu -> softmax over 25 taps -> sum attn*g -> + bias.
__global__ __launch_bounds__(128) void soft_kernel(
    const float* __restrict__ corrG, const float* __restrict__ gG,
    const float* __restrict__ bc, float* __restrict__ out)
{
    const int rr = blockIdx.x;           // b*H + r
    const int b  = rr >> 7;
    const int r  = rr & 127;
    const int w  = threadIdx.x;

    float v[25], m = 0.f;
#pragma unroll
    for (int i = 0; i < 5; ++i) {
        const float* c0 = corrG + (size_t)((rr * 5 + i) * 2) * (5 * W);
#pragma unroll
        for (int j = 0; j < 5; ++j) {
            v[i * 5 + j] = fmaxf(c0[j * W + w] + c0[5 * W + j * W + w], 0.f);
            m = fmaxf(m, v[i * 5 + j]);
        }
    }
    float sum = 0.f, num = 0.f;
#pragma unroll
    for (int i = 0; i < 5; ++i) {
        const int  rt  = r - 4 + 2 * i;
        const bool riv = (unsigned)rt < (unsigned)H;
        const size_t gb = ((size_t)(b * H + (riv ? rt : 0))) * 2 * W;
#pragma unroll
        for (int j = 0; j < 5; ++j) {
            const float e = __expf(v[i * 5 + j] - m);
            sum += e;
            const int  wt = w - 4 + 2 * j;
            const bool ok = riv && ((unsigned)wt < (unsigned)W);
            const int  wi = ok ? wt : 0;
            const float gv = gG[gb + wi] + gG[gb + W + wi];
            num = fmaf(e, ok ? gv : 0.f, num);
        }
    }
    out[(size_t)rr * W + w] = num / sum + bc[0];
}

extern "C" void kernel_launch(void* const* d_in, const int* in_sizes, int n_in,
                              void* d_out, int out_size, void* d_ws, size_t ws_size,
                              hipStream_t stream) {
    const float* feat = (const float*)d_in[0];
    const float* wcls = (const float*)d_in[1];
    const float* bcls = (const float*)d_in[2];
    float* outp  = (float*)d_out;
    float* corrG = (float*)d_ws;                        // 512*5*2*640*4 = 13.1 MB
    float* gG    = corrG + (size_t)512 * 5 * 2 * 5 * W; // 512*2*128*4   = 0.5 MB

    corr_kernel<<<dim3(5120), dim3(128), 0, stream>>>(feat, wcls, corrG, gG);
    soft_kernel<<<dim3(512), dim3(128), 0, stream>>>(corrG, gG, bcls, outp);
}